// Round 8
// baseline (719.772 us; speedup 1.0000x reference)
//
#include <hip/hip_runtime.h>
#include <math.h>

#define H 300
#define BB 64
#define TT 512
#define VV 50257
#define KC 30
#define TCHUNK 128   // rnn steps per dispatch (diagnostic 4-way split, R8)

typedef float v2f __attribute__((ext_vector_type(2)));

// ---------- transpose 300x300: out[r][c] = in[c][r] (U only) ----------
__global__ void transpose_k(const float* __restrict__ in, float* __restrict__ out) {
    int idx = blockIdx.x * blockDim.x + threadIdx.x;
    if (idx < H * H) {
        int r = idx / H, c = idx - r * H;
        out[idx] = in[c * H + r];
    }
}

// ---------- ux[t][b][g] = sum_h emb[tok[b][t]][h] * U[g][h] ----------
__global__ __launch_bounds__(256) void ux_k(const int* __restrict__ tokens,
                                            const float* __restrict__ emb,
                                            const float* __restrict__ Ut,   // Ut[h][g] = U[g][h]
                                            float* __restrict__ ux) {
    __shared__ __align__(16) float x_s[KC][BB];
    __shared__ __align__(16) float ut_s[KC][304];
    __shared__ int tok_s[BB];

    const int t = blockIdx.x;
    const int tid = threadIdx.x;
    if (tid < BB) tok_s[tid] = tokens[tid * TT + t];

    const int tb = tid >> 4;
    const int tg = tid & 15;
    const int b0 = tb * 4;
    const int g0 = tg * 20;
    const bool active = (tg < 15);

    v2f acc[4][10];
#pragma unroll
    for (int i = 0; i < 4; ++i)
#pragma unroll
        for (int j = 0; j < 10; ++j) acc[i][j] = (v2f){0.f, 0.f};

    __syncthreads();

    for (int h0 = 0; h0 < H; h0 += KC) {
        for (int i = tid; i < BB * 32; i += 256) {
            int b = i >> 5, k = i & 31;
            if (k < KC) x_s[k][b] = emb[tok_s[b] * H + h0 + k];
        }
        for (int i = tid; i < KC * H; i += 256) {
            int k = i / H, g = i - k * H;
            ut_s[k][g] = Ut[(h0 + k) * H + g];
        }
        __syncthreads();
        if (active) {
#pragma unroll 2
            for (int k = 0; k < KC; ++k) {
                float4 xa = *reinterpret_cast<const float4*>(&x_s[k][b0]);
                float4 u0 = *reinterpret_cast<const float4*>(&ut_s[k][g0 + 0]);
                float4 u1 = *reinterpret_cast<const float4*>(&ut_s[k][g0 + 4]);
                float4 u2 = *reinterpret_cast<const float4*>(&ut_s[k][g0 + 8]);
                float4 u3 = *reinterpret_cast<const float4*>(&ut_s[k][g0 + 12]);
                float4 u4 = *reinterpret_cast<const float4*>(&ut_s[k][g0 + 16]);
                const float xr[4] = {xa.x, xa.y, xa.z, xa.w};
                const v2f ur[10] = {{u0.x, u0.y}, {u0.z, u0.w},
                                    {u1.x, u1.y}, {u1.z, u1.w},
                                    {u2.x, u2.y}, {u2.z, u2.w},
                                    {u3.x, u3.y}, {u3.z, u3.w},
                                    {u4.x, u4.y}, {u4.z, u4.w}};
#pragma unroll
                for (int i = 0; i < 4; ++i) {
                    const v2f xs = {xr[i], xr[i]};
#pragma unroll
                    for (int j = 0; j < 10; ++j)
                        acc[i][j] = __builtin_elementwise_fma(xs, ur[j], acc[i][j]);
                }
            }
        }
        __syncthreads();
    }

    if (active) {
#pragma unroll
        for (int i = 0; i < 4; ++i) {
            float* dst = ux + (t * BB + b0 + i) * H + g0;
#pragma unroll
            for (int jq = 0; jq < 5; ++jq) {
                *reinterpret_cast<float4*>(dst + jq * 4) =
                    make_float4(acc[i][2 * jq].x, acc[i][2 * jq].y,
                                acc[i][2 * jq + 1].x, acc[i][2 * jq + 1].y);
            }
        }
    }
}

// ---------- recurrence: one block per batch, 768 threads (12 waves) ----------
// v9 = R7's v8 structure (best measured: 408us full-length), split into 4
// dispatches of TCHUNK=128 steps for DIAGNOSTIC VISIBILITY: top-5-by-duration
// always showed 5 rnn reps at 408, masking the constant ~300us of non-rnn
// time (analytic floor for ux+logits+transpose is only ~60-90us — ~200us is
// unaccounted). Quarters run ~105us, so any hidden kernel >=105us surfaces
// in the next round's table. h state round-trips through global f32 (exact)
// -> bit-identical. Cost ~25us (3 extra launches + W-register reload).
// R7 post-mortem (kept here as the rnn model): step=1913cy, busy=893,
// floor = ~380cy accvgpr copy-tax (likely not in VALUBusy) + ~500cy
// two-barrier+combine tail + ~150 initial LDS latency. Cross-CU row-split
// and in-wave shuffle-reduce variants both lose by arithmetic (sync latency
// / lane-utilization trade) — rnn is near its structural floor.
#define RNN_Q15(X) X(0) X(1) X(2) X(3) X(4) X(5) X(6) X(7) X(8) X(9) \
    X(10) X(11) X(12) X(13) X(14)

__global__ __attribute__((amdgpu_flat_work_group_size(768, 768), amdgpu_waves_per_eu(3, 3)))
void rnn_k(const float* __restrict__ W,     // W[g][h] read directly
           const float* __restrict__ ux,    // [T][B][H]
           const float* __restrict__ hin,   // [B][H] state at t0
           float* __restrict__ hout,        // [B][H] state at t0+TCHUNK
           int t0) {
    __shared__ __align__(16) float shpool[20800];   // 83,200 B -> 1 block/CU
    float* h_s = shpool;            // [0,304)    current hidden state
    float* p_s = shpool + 304;      // [304,1824) partials p_s[c][304]

    const int b = blockIdx.x;
    const int tid = threadIdx.x;
    const int tt = (tid < 750) ? tid : 749;  // tail lanes duplicate; writes guarded
    const int c  = tt / 150;                 // col chunk 0..4
    const int g2 = tt - c * 150;             // row-pair 0..149

    const float4* w0p = reinterpret_cast<const float4*>(W + (size_t)(g2      ) * H + c * 60);
    const float4* w1p = reinterpret_cast<const float4*>(W + (size_t)(g2 + 150) * H + c * 60);

    // Load W as float4 (coalesced), hold as v2f pairs (pk_fma operands).
#define RNN_DW(q) \
    float4 t0_##q = w0p[q]; \
    v2f w0l_##q = {t0_##q.x, t0_##q.y}; v2f w0h_##q = {t0_##q.z, t0_##q.w}; \
    float4 t1_##q = w1p[q]; \
    v2f w1l_##q = {t1_##q.x, t1_##q.y}; v2f w1h_##q = {t1_##q.z, t1_##q.w};
    RNN_Q15(RNN_DW)
#undef RNN_DW

    if (tid < H) h_s[tid] = hin[b * H + tid];

    const float* uxr = ux + (size_t)b * H + tid;   // valid when tid < 300
    float u = 0.f;
    if (tid < H) u = uxr[(size_t)t0 * (BB * H)];   // t = t0
    __syncthreads();

    const float4* hs4 = reinterpret_cast<const float4*>(h_s);
    const int c15 = c * 15;

#pragma unroll 1
    for (int t = t0; t < t0 + TCHUNK; ++t) {
        float n = 0.f;
        if (tid < H && t + 1 < TT)                 // prefetch t+1 under the FMAs
            n = uxr[(size_t)(t + 1) * (BB * H)];
        v2f a0l = {0.f, 0.f}, a0h = {0.f, 0.f};
        v2f a1l = {0.f, 0.f}, a1h = {0.f, 0.f};
#define RNN_FMA(q) { float4 h4 = hs4[c15 + q]; \
        v2f hl = {h4.x, h4.y}; v2f hh = {h4.z, h4.w}; \
        a0l = __builtin_elementwise_fma(w0l_##q, hl, a0l); \
        a0h = __builtin_elementwise_fma(w0h_##q, hh, a0h); \
        a1l = __builtin_elementwise_fma(w1l_##q, hl, a1l); \
        a1h = __builtin_elementwise_fma(w1h_##q, hh, a1h); }
        RNN_Q15(RNN_FMA)
#undef RNN_FMA
        float pA = (a0l.x + a0l.y) + (a0h.x + a0h.y);
        float pB = (a1l.x + a1l.y) + (a1h.x + a1h.y);
        if (tid < 750) {                           // stride-1, conflict-free
            p_s[c * 304 + g2      ] = pA;
            p_s[c * 304 + g2 + 150] = pB;
        }
        __syncthreads();                           // barrier #1
        if (tid < H) {                             // 300 combiners, 1 row each
            float z = p_s[tid] + u;                // ((((c0+u)+c1)+c2)+c3)+c4
            z += p_s[304 + tid];
            z += p_s[608 + tid];
            z += p_s[912 + tid];
            z += p_s[1216 + tid];
            float e = __expf(2.f * z);
            h_s[tid] = 1.f - 2.f * __builtin_amdgcn_rcpf(e + 1.f);
        }
        u = n;
        __syncthreads();                           // barrier #2
    }
    if (tid < H) hout[b * H + tid] = h_s[tid];
}

// ---------- logits: tiled GEMM  C[64,50257] = h[64,300] . Wout^T ----------
// Block tile [64 b x 128 v], 256 threads, micro-tile 8b x 4v per thread.
// h-chunks of 32 staged in LDS; Wout staged transposed (coalesced global
// reads, every byte read once -> 60 MB total at HBM rate).
// v9: inner product pk-ified (v_pk_fma_f32) — same per-element chains,
// bit-identical output; halves the ~10240 scalar FMA issues per thread.
__global__ __launch_bounds__(256) void logits_k(const float* __restrict__ hlast,
                                                const float* __restrict__ Wout,
                                                const float* __restrict__ bout,
                                                float* __restrict__ out) {
    __shared__ __align__(16) float Ws[32 * 132];   // Ws[h'][v'], stride 132
    __shared__ __align__(16) float hs[32 * 76];    // hs[h'][b],  stride 76
    const int tid = threadIdx.x;
    const int tv = tid & 31;          // v' = tv*4
    const int tb = tid >> 5;          // b0 = tb*8
    const int v0 = blockIdx.x * 128;

    v2f acc[8][2];
#pragma unroll
    for (int i = 0; i < 8; ++i) {
        acc[i][0] = (v2f){0.f, 0.f};
        acc[i][1] = (v2f){0.f, 0.f};
    }

    for (int hb = 0; hb < H; hb += 32) {
        __syncthreads();
        {   // stage Wout tile transposed: thread -> (v'=tid>>1, half q=tid&1)
            const int vp = tid >> 1;
            const int hloc = (tid & 1) * 16;
            int vv = v0 + vp; if (vv > VV - 1) vv = VV - 1;
            const float* wrow = Wout + (size_t)vv * H + hb + hloc;
#pragma unroll
            for (int i = 0; i < 4; ++i) {
                const int hg = hb + hloc + i * 4;
                float4 val;
                if (hg + 3 < H) {
                    val = *reinterpret_cast<const float4*>(wrow + i * 4);
                } else {
                    val.x = (hg + 0 < H) ? wrow[i * 4 + 0] : 0.f;
                    val.y = (hg + 1 < H) ? wrow[i * 4 + 1] : 0.f;
                    val.z = (hg + 2 < H) ? wrow[i * 4 + 2] : 0.f;
                    val.w = (hg + 3 < H) ? wrow[i * 4 + 3] : 0.f;
                }
                Ws[(hloc + i * 4 + 0) * 132 + vp] = val.x;
                Ws[(hloc + i * 4 + 1) * 132 + vp] = val.y;
                Ws[(hloc + i * 4 + 2) * 132 + vp] = val.z;
                Ws[(hloc + i * 4 + 3) * 132 + vp] = val.w;
            }
        }
        {   // stage h tile transposed: thread -> (b=tid>>2, 8 h's)
            const int bb = tid >> 2;
            const int hl = (tid & 3) * 8;
            const float* hrow = hlast + bb * H + hb + hl;
#pragma unroll
            for (int i = 0; i < 2; ++i) {
                const int hg = hb + hl + i * 4;
                float4 val;
                if (hg + 3 < H) {
                    val = *reinterpret_cast<const float4*>(hrow + i * 4);
                } else {
                    val.x = (hg + 0 < H) ? hrow[i * 4 + 0] : 0.f;
                    val.y = (hg + 1 < H) ? hrow[i * 4 + 1] : 0.f;
                    val.z = (hg + 2 < H) ? hrow[i * 4 + 2] : 0.f;
                    val.w = (hg + 3 < H) ? hrow[i * 4 + 3] : 0.f;
                }
                hs[(hl + i * 4 + 0) * 76 + bb] = val.x;
                hs[(hl + i * 4 + 1) * 76 + bb] = val.y;
                hs[(hl + i * 4 + 2) * 76 + bb] = val.z;
                hs[(hl + i * 4 + 3) * 76 + bb] = val.w;
            }
        }
        __syncthreads();
        const float4* Ws4 = reinterpret_cast<const float4*>(Ws);  // stride 33
        const float4* hs4 = reinterpret_cast<const float4*>(hs);  // stride 19
#pragma unroll
        for (int h2 = 0; h2 < 32; ++h2) {
            float4 w4  = Ws4[h2 * 33 + tv];
            float4 h4a = hs4[h2 * 19 + tb * 2];
            float4 h4b = hs4[h2 * 19 + tb * 2 + 1];
            const v2f wl = {w4.x, w4.y};
            const v2f wh = {w4.z, w4.w};
            const float hv[8] = {h4a.x, h4a.y, h4a.z, h4a.w,
                                 h4b.x, h4b.y, h4b.z, h4b.w};
#pragma unroll
            for (int bi = 0; bi < 8; ++bi) {
                const v2f hb2 = {hv[bi], hv[bi]};
                acc[bi][0] = __builtin_elementwise_fma(hb2, wl, acc[bi][0]);
                acc[bi][1] = __builtin_elementwise_fma(hb2, wh, acc[bi][1]);
            }
        }
    }

    const int vg = v0 + tv * 4;
    float4 bq;
    if (vg + 3 < VV) bq = *reinterpret_cast<const float4*>(bout + vg);
    else {
        bq.x = (vg + 0 < VV) ? bout[vg + 0] : 0.f;
        bq.y = (vg + 1 < VV) ? bout[vg + 1] : 0.f;
        bq.z = (vg + 2 < VV) ? bout[vg + 2] : 0.f;
        bq.w = (vg + 3 < VV) ? bout[vg + 3] : 0.f;
    }
#pragma unroll
    for (int bi = 0; bi < 8; ++bi) {
        const int bb = tb * 8 + bi;
        float* op = out + (size_t)bb * VV + vg;   // VV odd -> rows not 16B-aligned: scalar stores
        if (vg + 0 < VV) op[0] = acc[bi][0].x + bq.x;
        if (vg + 1 < VV) op[1] = acc[bi][0].y + bq.y;
        if (vg + 2 < VV) op[2] = acc[bi][1].x + bq.z;
        if (vg + 3 < VV) op[3] = acc[bi][1].y + bq.w;
    }
}

extern "C" void kernel_launch(void* const* d_in, const int* in_sizes, int n_in,
                              void* d_out, int out_size, void* d_ws, size_t ws_size,
                              hipStream_t stream) {
    const float* ihs    = (const float*)d_in[0];
    const int*   tokens = (const int*)  d_in[1];
    const float* emb    = (const float*)d_in[2];
    const float* W      = (const float*)d_in[3];
    const float* U      = (const float*)d_in[4];
    const float* Wout   = (const float*)d_in[5];
    const float* bout   = (const float*)d_in[6];
    float* out = (float*)d_out;

    char* ws = (char*)d_ws;
    float* Ut     = (float*)(ws + 0);          // 360,000 B
    float* hstate = (float*)(ws + 400000);     // 76,800 B
    float* ux     = (float*)(ws + 1048576);    // 39,321,600 B  [T][B][H]

    const int tp_blocks = (H * H + 255) / 256;
    transpose_k<<<tp_blocks, 256, 0, stream>>>(U, Ut);
    ux_k<<<TT, 256, 0, stream>>>(tokens, emb, Ut, ux);
    rnn_k<<<BB, 768, 0, stream>>>(W, ux, ihs,    hstate, 0);
    rnn_k<<<BB, 768, 0, stream>>>(W, ux, hstate, hstate, 128);
    rnn_k<<<BB, 768, 0, stream>>>(W, ux, hstate, hstate, 256);
    rnn_k<<<BB, 768, 0, stream>>>(W, ux, hstate, hstate, 384);
    logits_k<<<(VV + 127) / 128, 256, 0, stream>>>(hstate, Wout, bout, out);
}

// Round 9
// 703.997 us; speedup vs baseline: 1.0224x; 1.0224x over previous
//
#include <hip/hip_runtime.h>
#include <math.h>

#define H 300
#define BB 64
#define TT 512
#define VV 50257
#define KC 30

typedef float v2f __attribute__((ext_vector_type(2)));

// ---------- transpose 300x300: out[r][c] = in[c][r] (U only) ----------
__global__ void transpose_k(const float* __restrict__ in, float* __restrict__ out) {
    int idx = blockIdx.x * blockDim.x + threadIdx.x;
    if (idx < H * H) {
        int r = idx / H, c = idx - r * H;
        out[idx] = in[c * H + r];
    }
}

// ---------- ux[t][b][g] = sum_h emb[tok[b][t]][h] * U[g][h] ----------
// v10 (R8 post-mortem): ux_k was the hidden 146us kernel. Two findings:
// (1) VGPR_Count=72 < 80-float acc -> the backend halves the unified
//     waves-per-EU budget into arch/AGPR and the ACCUMULATORS were partly
//     AGPR-parked (read+write copy per FMA -> 3x VALU issue, 61us busy vs
//     19us pk floor). Fix: amdgpu_waves_per_eu(2,2) -> unified budget 256 ->
//     arch grant ~112-128 >= the ~119-float working set. LDS 44.9KB -> 2
//     blocks/CU, grid 512 = 2/CU exact.
// (2) SQ_LDS_BANK_CONFLICT=9.6M: x_s[k][b] staging writes vary k at
//     stride-64 floats -> 32-way conflict (512blk x 4w x 10chunks x 8iters
//     x ~56cy = 9.2M, matches). Fix: stride 68 -> banks 4k%32 -> 8-way
//     (~2.8x vs 11x); compute b128 reads stay 16B-aligned (68k+4tb ≡ 0 mod 4).
__global__ __attribute__((amdgpu_flat_work_group_size(256, 256), amdgpu_waves_per_eu(2, 2)))
void ux_k(const int* __restrict__ tokens,
          const float* __restrict__ emb,
          const float* __restrict__ Ut,   // Ut[h][g] = U[g][h]
          float* __restrict__ ux) {
    __shared__ __align__(16) float x_s[KC][68];    // stride 68: 8-way not 32-way
    __shared__ __align__(16) float ut_s[KC][304];
    __shared__ int tok_s[BB];

    const int t = blockIdx.x;
    const int tid = threadIdx.x;
    if (tid < BB) tok_s[tid] = tokens[tid * TT + t];

    const int tb = tid >> 4;
    const int tg = tid & 15;
    const int b0 = tb * 4;
    const int g0 = tg * 20;
    const bool active = (tg < 15);

    v2f acc[4][10];
#pragma unroll
    for (int i = 0; i < 4; ++i)
#pragma unroll
        for (int j = 0; j < 10; ++j) acc[i][j] = (v2f){0.f, 0.f};

    __syncthreads();

    for (int h0 = 0; h0 < H; h0 += KC) {
        for (int i = tid; i < BB * 32; i += 256) {
            int b = i >> 5, k = i & 31;
            if (k < KC) x_s[k][b] = emb[tok_s[b] * H + h0 + k];
        }
        for (int i = tid; i < KC * H; i += 256) {
            int k = i / H, g = i - k * H;
            ut_s[k][g] = Ut[(h0 + k) * H + g];
        }
        __syncthreads();
        if (active) {
#pragma unroll 2
            for (int k = 0; k < KC; ++k) {
                float4 xa = *reinterpret_cast<const float4*>(&x_s[k][b0]);
                float4 u0 = *reinterpret_cast<const float4*>(&ut_s[k][g0 + 0]);
                float4 u1 = *reinterpret_cast<const float4*>(&ut_s[k][g0 + 4]);
                float4 u2 = *reinterpret_cast<const float4*>(&ut_s[k][g0 + 8]);
                float4 u3 = *reinterpret_cast<const float4*>(&ut_s[k][g0 + 12]);
                float4 u4 = *reinterpret_cast<const float4*>(&ut_s[k][g0 + 16]);
                const float xr[4] = {xa.x, xa.y, xa.z, xa.w};
                const v2f ur[10] = {{u0.x, u0.y}, {u0.z, u0.w},
                                    {u1.x, u1.y}, {u1.z, u1.w},
                                    {u2.x, u2.y}, {u2.z, u2.w},
                                    {u3.x, u3.y}, {u3.z, u3.w},
                                    {u4.x, u4.y}, {u4.z, u4.w}};
#pragma unroll
                for (int i = 0; i < 4; ++i) {
                    const v2f xs = {xr[i], xr[i]};
#pragma unroll
                    for (int j = 0; j < 10; ++j)
                        acc[i][j] = __builtin_elementwise_fma(xs, ur[j], acc[i][j]);
                }
            }
        }
        __syncthreads();
    }

    if (active) {
#pragma unroll
        for (int i = 0; i < 4; ++i) {
            float* dst = ux + (t * BB + b0 + i) * H + g0;
#pragma unroll
            for (int jq = 0; jq < 5; ++jq) {
                *reinterpret_cast<float4*>(dst + jq * 4) =
                    make_float4(acc[i][2 * jq].x, acc[i][2 * jq].y,
                                acc[i][2 * jq + 1].x, acc[i][2 * jq + 1].y);
            }
        }
    }
}

// ---------- recurrence: one block per batch, 768 threads (12 waves) ----------
// v10 = R7's v8 (best measured: 408us), merged back to a single dispatch
// (R8's 4-way diagnostic split cost ~14us and served its purpose).
// Model (R7/R8): step = 1913cy, VALU busy 893; floor = ~380cy accvgpr copy
// tax (backend halves the unified budget: grants 84 arch of 170 at 3 waves
// — W half-AGPR'd, invariant across decompositions) + ~500cy two-barrier +
// combine tail + latency. 2-wave variants are latency-bound (R6: 451us at
// 44% busy); 3-wave pk is the measured optimum.
#define RNN_Q15(X) X(0) X(1) X(2) X(3) X(4) X(5) X(6) X(7) X(8) X(9) \
    X(10) X(11) X(12) X(13) X(14)

__global__ __attribute__((amdgpu_flat_work_group_size(768, 768), amdgpu_waves_per_eu(3, 3)))
void rnn_k(const float* __restrict__ W,     // W[g][h] read directly
           const float* __restrict__ ux,    // [T][B][H]
           const float* __restrict__ ihs,
           float* __restrict__ hlast) {
    __shared__ __align__(16) float shpool[20800];   // 83,200 B -> 1 block/CU
    float* h_s = shpool;            // [0,304)    current hidden state
    float* p_s = shpool + 304;      // [304,1824) partials p_s[c][304]

    const int b = blockIdx.x;
    const int tid = threadIdx.x;
    const int tt = (tid < 750) ? tid : 749;  // tail lanes duplicate; writes guarded
    const int c  = tt / 150;                 // col chunk 0..4
    const int g2 = tt - c * 150;             // row-pair 0..149

    const float4* w0p = reinterpret_cast<const float4*>(W + (size_t)(g2      ) * H + c * 60);
    const float4* w1p = reinterpret_cast<const float4*>(W + (size_t)(g2 + 150) * H + c * 60);

    // Load W as float4 (coalesced), hold as v2f pairs (pk_fma operands).
#define RNN_DW(q) \
    float4 t0_##q = w0p[q]; \
    v2f w0l_##q = {t0_##q.x, t0_##q.y}; v2f w0h_##q = {t0_##q.z, t0_##q.w}; \
    float4 t1_##q = w1p[q]; \
    v2f w1l_##q = {t1_##q.x, t1_##q.y}; v2f w1h_##q = {t1_##q.z, t1_##q.w};
    RNN_Q15(RNN_DW)
#undef RNN_DW

    if (tid < H) h_s[tid] = ihs[b * H + tid];

    const float* uxr = ux + (size_t)b * H + tid;   // valid when tid < 300
    float u = 0.f;
    if (tid < H) u = uxr[0];                       // t = 0
    __syncthreads();

    const float4* hs4 = reinterpret_cast<const float4*>(h_s);
    const int c15 = c * 15;

#pragma unroll 1
    for (int t = 0; t < TT; ++t) {
        float n = 0.f;
        if (tid < H && t + 1 < TT)                 // prefetch t+1 under the FMAs
            n = uxr[(size_t)(t + 1) * (BB * H)];
        v2f a0l = {0.f, 0.f}, a0h = {0.f, 0.f};
        v2f a1l = {0.f, 0.f}, a1h = {0.f, 0.f};
#define RNN_FMA(q) { float4 h4 = hs4[c15 + q]; \
        v2f hl = {h4.x, h4.y}; v2f hh = {h4.z, h4.w}; \
        a0l = __builtin_elementwise_fma(w0l_##q, hl, a0l); \
        a0h = __builtin_elementwise_fma(w0h_##q, hh, a0h); \
        a1l = __builtin_elementwise_fma(w1l_##q, hl, a1l); \
        a1h = __builtin_elementwise_fma(w1h_##q, hh, a1h); }
        RNN_Q15(RNN_FMA)
#undef RNN_FMA
        float pA = (a0l.x + a0l.y) + (a0h.x + a0h.y);
        float pB = (a1l.x + a1l.y) + (a1h.x + a1h.y);
        if (tid < 750) {                           // stride-1, conflict-free
            p_s[c * 304 + g2      ] = pA;
            p_s[c * 304 + g2 + 150] = pB;
        }
        __syncthreads();                           // barrier #1
        if (tid < H) {                             // 300 combiners, 1 row each
            float z = p_s[tid] + u;                // ((((c0+u)+c1)+c2)+c3)+c4
            z += p_s[304 + tid];
            z += p_s[608 + tid];
            z += p_s[912 + tid];
            z += p_s[1216 + tid];
            float e = __expf(2.f * z);
            h_s[tid] = 1.f - 2.f * __builtin_amdgcn_rcpf(e + 1.f);
        }
        u = n;
        __syncthreads();                           // barrier #2
    }
    if (tid < H) hlast[b * H + tid] = h_s[tid];
}

// ---------- logits: tiled GEMM  C[64,50257] = h[64,300] . Wout^T ----------
// Block tile [64 b x 128 v], 256 threads, micro-tile 8b x 4v per thread.
// h-chunks of 32 staged in LDS; Wout staged transposed (coalesced global
// reads, every byte read once -> 60 MB total at HBM rate). pk-ified (R8).
__global__ __launch_bounds__(256) void logits_k(const float* __restrict__ hlast,
                                                const float* __restrict__ Wout,
                                                const float* __restrict__ bout,
                                                float* __restrict__ out) {
    __shared__ __align__(16) float Ws[32 * 132];   // Ws[h'][v'], stride 132
    __shared__ __align__(16) float hs[32 * 76];    // hs[h'][b],  stride 76
    const int tid = threadIdx.x;
    const int tv = tid & 31;          // v' = tv*4
    const int tb = tid >> 5;          // b0 = tb*8
    const int v0 = blockIdx.x * 128;

    v2f acc[8][2];
#pragma unroll
    for (int i = 0; i < 8; ++i) {
        acc[i][0] = (v2f){0.f, 0.f};
        acc[i][1] = (v2f){0.f, 0.f};
    }

    for (int hb = 0; hb < H; hb += 32) {
        __syncthreads();
        {   // stage Wout tile transposed: thread -> (v'=tid>>1, half q=tid&1)
            const int vp = tid >> 1;
            const int hloc = (tid & 1) * 16;
            int vv = v0 + vp; if (vv > VV - 1) vv = VV - 1;
            const float* wrow = Wout + (size_t)vv * H + hb + hloc;
#pragma unroll
            for (int i = 0; i < 4; ++i) {
                const int hg = hb + hloc + i * 4;
                float4 val;
                if (hg + 3 < H) {
                    val = *reinterpret_cast<const float4*>(wrow + i * 4);
                } else {
                    val.x = (hg + 0 < H) ? wrow[i * 4 + 0] : 0.f;
                    val.y = (hg + 1 < H) ? wrow[i * 4 + 1] : 0.f;
                    val.z = (hg + 2 < H) ? wrow[i * 4 + 2] : 0.f;
                    val.w = (hg + 3 < H) ? wrow[i * 4 + 3] : 0.f;
                }
                Ws[(hloc + i * 4 + 0) * 132 + vp] = val.x;
                Ws[(hloc + i * 4 + 1) * 132 + vp] = val.y;
                Ws[(hloc + i * 4 + 2) * 132 + vp] = val.z;
                Ws[(hloc + i * 4 + 3) * 132 + vp] = val.w;
            }
        }
        {   // stage h tile transposed: thread -> (b=tid>>2, 8 h's)
            const int bb = tid >> 2;
            const int hl = (tid & 3) * 8;
            const float* hrow = hlast + bb * H + hb + hl;
#pragma unroll
            for (int i = 0; i < 2; ++i) {
                const int hg = hb + hl + i * 4;
                float4 val;
                if (hg + 3 < H) {
                    val = *reinterpret_cast<const float4*>(hrow + i * 4);
                } else {
                    val.x = (hg + 0 < H) ? hrow[i * 4 + 0] : 0.f;
                    val.y = (hg + 1 < H) ? hrow[i * 4 + 1] : 0.f;
                    val.z = (hg + 2 < H) ? hrow[i * 4 + 2] : 0.f;
                    val.w = (hg + 3 < H) ? hrow[i * 4 + 3] : 0.f;
                }
                hs[(hl + i * 4 + 0) * 76 + bb] = val.x;
                hs[(hl + i * 4 + 1) * 76 + bb] = val.y;
                hs[(hl + i * 4 + 2) * 76 + bb] = val.z;
                hs[(hl + i * 4 + 3) * 76 + bb] = val.w;
            }
        }
        __syncthreads();
        const float4* Ws4 = reinterpret_cast<const float4*>(Ws);  // stride 33
        const float4* hs4 = reinterpret_cast<const float4*>(hs);  // stride 19
#pragma unroll
        for (int h2 = 0; h2 < 32; ++h2) {
            float4 w4  = Ws4[h2 * 33 + tv];
            float4 h4a = hs4[h2 * 19 + tb * 2];
            float4 h4b = hs4[h2 * 19 + tb * 2 + 1];
            const v2f wl = {w4.x, w4.y};
            const v2f wh = {w4.z, w4.w};
            const float hv[8] = {h4a.x, h4a.y, h4a.z, h4a.w,
                                 h4b.x, h4b.y, h4b.z, h4b.w};
#pragma unroll
            for (int bi = 0; bi < 8; ++bi) {
                const v2f hb2 = {hv[bi], hv[bi]};
                acc[bi][0] = __builtin_elementwise_fma(hb2, wl, acc[bi][0]);
                acc[bi][1] = __builtin_elementwise_fma(hb2, wh, acc[bi][1]);
            }
        }
    }

    const int vg = v0 + tv * 4;
    float4 bq;
    if (vg + 3 < VV) bq = *reinterpret_cast<const float4*>(bout + vg);
    else {
        bq.x = (vg + 0 < VV) ? bout[vg + 0] : 0.f;
        bq.y = (vg + 1 < VV) ? bout[vg + 1] : 0.f;
        bq.z = (vg + 2 < VV) ? bout[vg + 2] : 0.f;
        bq.w = (vg + 3 < VV) ? bout[vg + 3] : 0.f;
    }
#pragma unroll
    for (int bi = 0; bi < 8; ++bi) {
        const int bb = tb * 8 + bi;
        float* op = out + (size_t)bb * VV + vg;   // VV odd -> rows not 16B-aligned: scalar stores
        if (vg + 0 < VV) op[0] = acc[bi][0].x + bq.x;
        if (vg + 1 < VV) op[1] = acc[bi][0].y + bq.y;
        if (vg + 2 < VV) op[2] = acc[bi][1].x + bq.z;
        if (vg + 3 < VV) op[3] = acc[bi][1].y + bq.w;
    }
}

extern "C" void kernel_launch(void* const* d_in, const int* in_sizes, int n_in,
                              void* d_out, int out_size, void* d_ws, size_t ws_size,
                              hipStream_t stream) {
    const float* ihs    = (const float*)d_in[0];
    const int*   tokens = (const int*)  d_in[1];
    const float* emb    = (const float*)d_in[2];
    const float* W      = (const float*)d_in[3];
    const float* U      = (const float*)d_in[4];
    const float* Wout   = (const float*)d_in[5];
    const float* bout   = (const float*)d_in[6];
    float* out = (float*)d_out;

    char* ws = (char*)d_ws;
    float* Ut    = (float*)(ws + 0);          // 360,000 B
    float* hlast = (float*)(ws + 400000);     // 76,800 B
    float* ux    = (float*)(ws + 1048576);    // 39,321,600 B  [T][B][H]

    const int tp_blocks = (H * H + 255) / 256;
    transpose_k<<<tp_blocks, 256, 0, stream>>>(U, Ut);
    ux_k<<<TT, 256, 0, stream>>>(tokens, emb, Ut, ux);
    rnn_k<<<BB, 768, 0, stream>>>(W, ux, ihs, hlast);
    logits_k<<<(VV + 127) / 128, 256, 0, stream>>>(hlast, Wout, bout, out);
}

// Round 10
// 690.210 us; speedup vs baseline: 1.0428x; 1.0200x over previous
//
#include <hip/hip_runtime.h>
#include <math.h>

#define H 300
#define BB 64
#define TT 512
#define VV 50257
#define KC 30

typedef float v2f __attribute__((ext_vector_type(2)));

// ---------- transpose 300x300: out[r][c] = in[c][r] (U only) ----------
__global__ void transpose_k(const float* __restrict__ in, float* __restrict__ out) {
    int idx = blockIdx.x * blockDim.x + threadIdx.x;
    if (idx < H * H) {
        int r = idx / H, c = idx - r * H;
        out[idx] = in[c * H + r];
    }
}

// ---------- ux[t][b][g] = sum_h emb[tok[b][t]][h] * U[g][h] ----------
// v11 = R8 structure (default occupancy: 3 blocks/CU by LDS) + stride-68 x_s
// (R8's 9.6M LDS conflict cycles were the x_s[k][b] staging writes at
// stride-64 = 32-way; 68 -> 8-way). R9's waves_per_eu(2,2) experiment was
// net-neutral (occupancy loss canceled the reg-grant gain) -> reverted.
__global__ __launch_bounds__(256) void ux_k(const int* __restrict__ tokens,
                                            const float* __restrict__ emb,
                                            const float* __restrict__ Ut,   // Ut[h][g] = U[g][h]
                                            float* __restrict__ ux) {
    __shared__ __align__(16) float x_s[KC][68];    // stride 68: 8-way not 32-way
    __shared__ __align__(16) float ut_s[KC][304];
    __shared__ int tok_s[BB];

    const int t = blockIdx.x;
    const int tid = threadIdx.x;
    if (tid < BB) tok_s[tid] = tokens[tid * TT + t];

    const int tb = tid >> 4;
    const int tg = tid & 15;
    const int b0 = tb * 4;
    const int g0 = tg * 20;
    const bool active = (tg < 15);

    v2f acc[4][10];
#pragma unroll
    for (int i = 0; i < 4; ++i)
#pragma unroll
        for (int j = 0; j < 10; ++j) acc[i][j] = (v2f){0.f, 0.f};

    __syncthreads();

    for (int h0 = 0; h0 < H; h0 += KC) {
        for (int i = tid; i < BB * 32; i += 256) {
            int b = i >> 5, k = i & 31;
            if (k < KC) x_s[k][b] = emb[tok_s[b] * H + h0 + k];
        }
        for (int i = tid; i < KC * H; i += 256) {
            int k = i / H, g = i - k * H;
            ut_s[k][g] = Ut[(h0 + k) * H + g];
        }
        __syncthreads();
        if (active) {
#pragma unroll 2
            for (int k = 0; k < KC; ++k) {
                float4 xa = *reinterpret_cast<const float4*>(&x_s[k][b0]);
                float4 u0 = *reinterpret_cast<const float4*>(&ut_s[k][g0 + 0]);
                float4 u1 = *reinterpret_cast<const float4*>(&ut_s[k][g0 + 4]);
                float4 u2 = *reinterpret_cast<const float4*>(&ut_s[k][g0 + 8]);
                float4 u3 = *reinterpret_cast<const float4*>(&ut_s[k][g0 + 12]);
                float4 u4 = *reinterpret_cast<const float4*>(&ut_s[k][g0 + 16]);
                const float xr[4] = {xa.x, xa.y, xa.z, xa.w};
                const v2f ur[10] = {{u0.x, u0.y}, {u0.z, u0.w},
                                    {u1.x, u1.y}, {u1.z, u1.w},
                                    {u2.x, u2.y}, {u2.z, u2.w},
                                    {u3.x, u3.y}, {u3.z, u3.w},
                                    {u4.x, u4.y}, {u4.z, u4.w}};
#pragma unroll
                for (int i = 0; i < 4; ++i) {
                    const v2f xs = {xr[i], xr[i]};
#pragma unroll
                    for (int j = 0; j < 10; ++j)
                        acc[i][j] = __builtin_elementwise_fma(xs, ur[j], acc[i][j]);
                }
            }
        }
        __syncthreads();
    }

    if (active) {
#pragma unroll
        for (int i = 0; i < 4; ++i) {
            float* dst = ux + (t * BB + b0 + i) * H + g0;
#pragma unroll
            for (int jq = 0; jq < 5; ++jq) {
                *reinterpret_cast<float4*>(dst + jq * 4) =
                    make_float4(acc[i][2 * jq].x, acc[i][2 * jq].y,
                                acc[i][2 * jq + 1].x, acc[i][2 * jq + 1].y);
            }
        }
    }
}

// ---------- recurrence: one block per batch, 768 threads (12 waves) ----------
// = R7's v8 (best measured 405-408us). Model: step 1913cy, VALU busy 893;
// floor = accvgpr copy tax (backend halves the unified budget; W half-AGPR'd,
// invariant across decompositions) + two-barrier+combine tail + latency.
// 2-wave variants latency-bound (R6); 3-wave pk is the measured optimum.
#define RNN_Q15(X) X(0) X(1) X(2) X(3) X(4) X(5) X(6) X(7) X(8) X(9) \
    X(10) X(11) X(12) X(13) X(14)

__global__ __attribute__((amdgpu_flat_work_group_size(768, 768), amdgpu_waves_per_eu(3, 3)))
void rnn_k(const float* __restrict__ W,     // W[g][h] read directly
           const float* __restrict__ ux,    // [T][B][H]
           const float* __restrict__ ihs,
           float* __restrict__ hlast) {
    __shared__ __align__(16) float shpool[20800];   // 83,200 B -> 1 block/CU
    float* h_s = shpool;            // [0,304)    current hidden state
    float* p_s = shpool + 304;      // [304,1824) partials p_s[c][304]

    const int b = blockIdx.x;
    const int tid = threadIdx.x;
    const int tt = (tid < 750) ? tid : 749;  // tail lanes duplicate; writes guarded
    const int c  = tt / 150;                 // col chunk 0..4
    const int g2 = tt - c * 150;             // row-pair 0..149

    const float4* w0p = reinterpret_cast<const float4*>(W + (size_t)(g2      ) * H + c * 60);
    const float4* w1p = reinterpret_cast<const float4*>(W + (size_t)(g2 + 150) * H + c * 60);

    // Load W as float4 (coalesced), hold as v2f pairs (pk_fma operands).
#define RNN_DW(q) \
    float4 t0_##q = w0p[q]; \
    v2f w0l_##q = {t0_##q.x, t0_##q.y}; v2f w0h_##q = {t0_##q.z, t0_##q.w}; \
    float4 t1_##q = w1p[q]; \
    v2f w1l_##q = {t1_##q.x, t1_##q.y}; v2f w1h_##q = {t1_##q.z, t1_##q.w};
    RNN_Q15(RNN_DW)
#undef RNN_DW

    if (tid < H) h_s[tid] = ihs[b * H + tid];

    const float* uxr = ux + (size_t)b * H + tid;   // valid when tid < 300
    float u = 0.f;
    if (tid < H) u = uxr[0];                       // t = 0
    __syncthreads();

    const float4* hs4 = reinterpret_cast<const float4*>(h_s);
    const int c15 = c * 15;

#pragma unroll 1
    for (int t = 0; t < TT; ++t) {
        float n = 0.f;
        if (tid < H && t + 1 < TT)                 // prefetch t+1 under the FMAs
            n = uxr[(size_t)(t + 1) * (BB * H)];
        v2f a0l = {0.f, 0.f}, a0h = {0.f, 0.f};
        v2f a1l = {0.f, 0.f}, a1h = {0.f, 0.f};
#define RNN_FMA(q) { float4 h4 = hs4[c15 + q]; \
        v2f hl = {h4.x, h4.y}; v2f hh = {h4.z, h4.w}; \
        a0l = __builtin_elementwise_fma(w0l_##q, hl, a0l); \
        a0h = __builtin_elementwise_fma(w0h_##q, hh, a0h); \
        a1l = __builtin_elementwise_fma(w1l_##q, hl, a1l); \
        a1h = __builtin_elementwise_fma(w1h_##q, hh, a1h); }
        RNN_Q15(RNN_FMA)
#undef RNN_FMA
        float pA = (a0l.x + a0l.y) + (a0h.x + a0h.y);
        float pB = (a1l.x + a1l.y) + (a1h.x + a1h.y);
        if (tid < 750) {                           // stride-1, conflict-free
            p_s[c * 304 + g2      ] = pA;
            p_s[c * 304 + g2 + 150] = pB;
        }
        __syncthreads();                           // barrier #1
        if (tid < H) {                             // 300 combiners, 1 row each
            float z = p_s[tid] + u;                // ((((c0+u)+c1)+c2)+c3)+c4
            z += p_s[304 + tid];
            z += p_s[608 + tid];
            z += p_s[912 + tid];
            z += p_s[1216 + tid];
            float e = __expf(2.f * z);
            h_s[tid] = 1.f - 2.f * __builtin_amdgcn_rcpf(e + 1.f);
        }
        u = n;
        __syncthreads();                           // barrier #2
    }
    if (tid < H) hlast[b * H + tid] = h_s[tid];
}

// ---------- logits: tiled GEMM  C[64,50257] = h[64,300] . Wout^T ----------
// v11 (R9 accounting: logits was ~120us hidden below rnn in top-5 — grid 393
// = 1.5 waves/SIMD avg, half the CUs on a single block, 10 load->barrier
// rounds with no latency hiding, 300-float-strided staging reads ->
// 60MB at 460GB/s effective). Rewrite: tile [64b x 64v], grid 786 = 3
// blocks/CU, 12 waves/CU; micro-tile 4b x 4v (acc 16 — far below any reg
// grant); staging reads are 2 full 128B lines per row; compute LDS reads are
// broadcast (hs) / 2-way (Ws). Per-output k-order unchanged -> bit-identical.
__global__ __launch_bounds__(256) void logits_k(const float* __restrict__ hlast,
                                                const float* __restrict__ Wout,
                                                const float* __restrict__ bout,
                                                float* __restrict__ out) {
    __shared__ __align__(16) float Ws[32][68];   // Ws[h'][v']
    __shared__ __align__(16) float hs[32][68];   // hs[h'][b]
    const int tid = threadIdx.x;
    const int tv = tid & 15;          // v-group: v = 4*tv
    const int tb = tid >> 4;          // b-group: b = 4*tb
    const int v0 = blockIdx.x * 64;

    v2f acc[4][2];                    // [bi][v-pair]
#pragma unroll
    for (int i = 0; i < 4; ++i) {
        acc[i][0] = (v2f){0.f, 0.f};
        acc[i][1] = (v2f){0.f, 0.f};
    }

    const int vp = tid >> 2;          // staging row 0..63
    const int h8 = (tid & 3) * 8;     // staging col start (8 floats)
    int vv = v0 + vp; if (vv > VV - 1) vv = VV - 1;
    const float* wrow = Wout + (size_t)vv * H;
    const float* hrow = hlast + (size_t)vp * H;

    for (int hb = 0; hb < H; hb += 32) {
        __syncthreads();
        // stage Wout tile (transposed) and h tile (transposed), zero-padded
#pragma unroll
        for (int i = 0; i < 2; ++i) {
            const int hg = hb + h8 + i * 4;
            float4 wv, hv;
            if (hg + 3 < H) {
                wv = *reinterpret_cast<const float4*>(wrow + hg);
                hv = *reinterpret_cast<const float4*>(hrow + hg);
            } else {
                wv.x = (hg + 0 < H) ? wrow[hg + 0] : 0.f;
                wv.y = (hg + 1 < H) ? wrow[hg + 1] : 0.f;
                wv.z = (hg + 2 < H) ? wrow[hg + 2] : 0.f;
                wv.w = (hg + 3 < H) ? wrow[hg + 3] : 0.f;
                hv.x = (hg + 0 < H) ? hrow[hg + 0] : 0.f;
                hv.y = (hg + 1 < H) ? hrow[hg + 1] : 0.f;
                hv.z = (hg + 2 < H) ? hrow[hg + 2] : 0.f;
                hv.w = (hg + 3 < H) ? hrow[hg + 3] : 0.f;
            }
            const int kl = h8 + i * 4;
            Ws[kl + 0][vp] = wv.x; Ws[kl + 1][vp] = wv.y;
            Ws[kl + 2][vp] = wv.z; Ws[kl + 3][vp] = wv.w;
            hs[kl + 0][vp] = hv.x; hs[kl + 1][vp] = hv.y;
            hs[kl + 2][vp] = hv.z; hs[kl + 3][vp] = hv.w;
        }
        __syncthreads();
#pragma unroll 8
        for (int k = 0; k < 32; ++k) {          // zero-padded tail is harmless
            float4 w4 = *reinterpret_cast<const float4*>(&Ws[k][tv * 4]);
            float4 h4 = *reinterpret_cast<const float4*>(&hs[k][tb * 4]);
            const v2f wl = {w4.x, w4.y};
            const v2f wh = {w4.z, w4.w};
            const float hvals[4] = {h4.x, h4.y, h4.z, h4.w};
#pragma unroll
            for (int bi = 0; bi < 4; ++bi) {
                const v2f hb2 = {hvals[bi], hvals[bi]};
                acc[bi][0] = __builtin_elementwise_fma(hb2, wl, acc[bi][0]);
                acc[bi][1] = __builtin_elementwise_fma(hb2, wh, acc[bi][1]);
            }
        }
    }

    const int vg = v0 + tv * 4;
    float bq[4];
#pragma unroll
    for (int j = 0; j < 4; ++j) bq[j] = (vg + j < VV) ? bout[vg + j] : 0.f;
#pragma unroll
    for (int bi = 0; bi < 4; ++bi) {
        const int bb = tb * 4 + bi;
        float* op = out + (size_t)bb * VV + vg;   // VV odd -> scalar stores
        if (vg + 0 < VV) op[0] = acc[bi][0].x + bq[0];
        if (vg + 1 < VV) op[1] = acc[bi][0].y + bq[1];
        if (vg + 2 < VV) op[2] = acc[bi][1].x + bq[2];
        if (vg + 3 < VV) op[3] = acc[bi][1].y + bq[3];
    }
}

extern "C" void kernel_launch(void* const* d_in, const int* in_sizes, int n_in,
                              void* d_out, int out_size, void* d_ws, size_t ws_size,
                              hipStream_t stream) {
    const float* ihs    = (const float*)d_in[0];
    const int*   tokens = (const int*)  d_in[1];
    const float* emb    = (const float*)d_in[2];
    const float* W      = (const float*)d_in[3];
    const float* U      = (const float*)d_in[4];
    const float* Wout   = (const float*)d_in[5];
    const float* bout   = (const float*)d_in[6];
    float* out = (float*)d_out;

    char* ws = (char*)d_ws;
    float* Ut    = (float*)(ws + 0);          // 360,000 B
    float* hlast = (float*)(ws + 400000);     // 76,800 B
    float* ux    = (float*)(ws + 1048576);    // 39,321,600 B  [T][B][H]

    const int tp_blocks = (H * H + 255) / 256;
    transpose_k<<<tp_blocks, 256, 0, stream>>>(U, Ut);
    ux_k<<<TT, 256, 0, stream>>>(tokens, emb, Ut, ux);
    rnn_k<<<BB, 768, 0, stream>>>(W, ux, ihs, hlast);
    logits_k<<<(VV + 63) / 64, 256, 0, stream>>>(hlast, Wout, bout, out);
}